// Round 8
// baseline (361.970 us; speedup 1.0000x reference)
//
#include <hip/hip_runtime.h>

#define NPTS 262144
#define DIM 64
#define KCODES 1024

typedef short bf16x8 __attribute__((ext_vector_type(8)));
typedef float f32x4 __attribute__((ext_vector_type(4)));
typedef short short8 __attribute__((ext_vector_type(8)));

// ---------- ws layout ----------
// gtile: tiled bf16 splits of eS=-2*emb: 64 kc-tiles * 3 splits * 2 chunks * 64 granules * 16B = 393216 B
// e2g:   1024 f32 at +393216
// candidate pairs are packed into iout (d_out indices region): u32 = i1 | (i2<<10)
#define GTILE_BYTES 393216
#define E2_OFF (GTILE_BYTES)

__device__ __forceinline__ unsigned short bf16_rne(float v) {
    unsigned int u = __float_as_uint(v);
    return (unsigned short)((u + 0x7FFFu + ((u >> 16) & 1u)) >> 16);
}
__device__ __forceinline__ float bf16_to_f32(unsigned short h) {
    return __uint_as_float(((unsigned int)h) << 16);
}

// e2[k] = sum emb[k][d]^2 — EXACT same accumulation as rounds 2-7 (passed absmax=0)
__global__ void vq_e2_kernel(const float* __restrict__ emb, float* __restrict__ e2) {
    int k = blockIdx.x * blockDim.x + threadIdx.x;
    if (k < KCODES) {
        const float4* row = reinterpret_cast<const float4*>(emb + k * DIM);
        float s = 0.f;
#pragma unroll
        for (int j = 0; j < DIM / 4; ++j) {
            float4 v = row[j];
            s = fmaf(v.x, v.x, s);
            s = fmaf(v.y, v.y, s);
            s = fmaf(v.z, v.z, s);
            s = fmaf(v.w, v.w, s);
        }
        e2[k] = s;
    }
}

// Tile eS=-2*emb into MFMA-granule order, 3-way bf16 split. (unchanged, proven)
__global__ void vq_tile_kernel(const float* __restrict__ emb, unsigned short* __restrict__ gtile) {
    int t = blockIdx.x * blockDim.x + threadIdx.x;
    if (t >= 64 * 3 * 2 * 64) return;
    int kc = t / 384;
    int r = t % 384;
    int s = r / 128;
    int r2 = r % 128;
    int chunk = r2 / 64;
    int l = r2 % 64;
    int code = kc * 16 + (l & 15);
    int dim0 = chunk * 32 + (l >> 4) * 8;
    const float* src = emb + code * DIM + dim0;
    short8 out;
#pragma unroll
    for (int e = 0; e < 8; ++e) {
        float v = -2.f * src[e];
        unsigned short hs = bf16_rne(v);
        float rr = v - bf16_to_f32(hs);
        unsigned short ms = bf16_rne(rr);
        float rr2 = rr - bf16_to_f32(ms);
        unsigned short ls = bf16_rne(rr2);
        out[e] = (short)((s == 0) ? hs : ((s == 1) ? ms : ls));
    }
    *reinterpret_cast<short8*>(gtile + (size_t)t * 8) = out;
}

// Main: 256 thr = 4 waves; wave owns 32 points (2 MFMA point-tiles).
// 16 rounds x 64 codes (24KB LDS) -> 5 blocks/CU by LDS; 16 waves/CU at ~72 VGPR.
// Single MFMA chain per T (C-init = e2); min/med3 top-2 update.
__global__ __launch_bounds__(256, 2) void vq_mfma_kernel(
    const float* __restrict__ x, const unsigned short* __restrict__ gtile,
    const float* __restrict__ e2g, float* __restrict__ candout) {
    __shared__ __align__(16) unsigned short etile[12288];  // 24 KB (64 codes)
    __shared__ float e2all[KCODES];                        // 4 KB, staged once

    const int tid = threadIdx.x;
    const int lane = tid & 63;
    const int wid = tid >> 6;
    const int ptbase = blockIdx.x * 128 + wid * 32;
    const int c16 = lane & 15;   // A-row / B-col / C-col index within tile
    const int hi = lane >> 4;    // k-subblock / C row group

    // ---- A-prep: load f32 x rows, split to bf16x8 frags in-register ----
    bf16x8 ah[2][2], am[2][2], al[2][2];
#pragma unroll
    for (int T = 0; T < 2; ++T) {
#pragma unroll
        for (int c = 0; c < 2; ++c) {
            const float* src = x + (size_t)(ptbase + T * 16 + c16) * DIM + c * 32 + hi * 8;
            float4 f0 = *reinterpret_cast<const float4*>(src);
            float4 f1 = *reinterpret_cast<const float4*>(src + 4);
            float va[8] = {f0.x, f0.y, f0.z, f0.w, f1.x, f1.y, f1.z, f1.w};
            bf16x8 vh, vm, vl;
#pragma unroll
            for (int e = 0; e < 8; ++e) {
                float v = va[e];
                unsigned short hs = bf16_rne(v);
                float rr = v - bf16_to_f32(hs);
                unsigned short ms = bf16_rne(rr);
                float rr2 = rr - bf16_to_f32(ms);
                unsigned short ls = bf16_rne(rr2);
                vh[e] = (short)hs; vm[e] = (short)ms; vl[e] = (short)ls;
            }
            ah[T][c] = vh; am[T][c] = vm; al[T][c] = vl;
        }
    }

    // stage e2 once (covered by round-0 post-stage barrier)
#pragma unroll
    for (int i = 0; i < 4; ++i) e2all[tid + i * 256] = e2g[tid + i * 256];

    float b1[2][4], b2[2][4];
    int i1[2][4], i2[2][4];
#pragma unroll
    for (int T = 0; T < 2; ++T)
#pragma unroll
        for (int r = 0; r < 4; ++r) { b1[T][r] = 3.4e38f; b2[T][r] = 3.4e38f; i1[T][r] = 0; i2[T][r] = 0; }

    const bf16x8* etile_v = reinterpret_cast<const bf16x8*>(etile);

    for (int R2 = 0; R2 < 16; ++R2) {  // 64 codes per round
        __syncthreads();  // protect previous round's readers
        const bf16x8* g8 = reinterpret_cast<const bf16x8*>(gtile) + R2 * 1536;
        bf16x8* l8 = reinterpret_cast<bf16x8*>(etile);
#pragma unroll
        for (int j = 0; j < 6; ++j) l8[tid + j * 256] = g8[tid + j * 256];
        __syncthreads();

#pragma unroll
        for (int kcL = 0; kcL < 4; ++kcL) {
            const int code_c = R2 * 64 + kcL * 16 + c16;
            const float e2v = e2all[code_c];
            f32x4 c[2];  // single accumulator chain per T, init = e2
            c[0] = (f32x4){e2v, e2v, e2v, e2v};
            c[1] = c[0];
#pragma unroll
            for (int es = 0; es < 3; ++es) {
                bf16x8 bc0 = etile_v[(kcL * 6 + es * 2 + 0) * 64 + lane];
                bf16x8 bc1 = etile_v[(kcL * 6 + es * 2 + 1) * 64 + lane];
                if (es == 0) {  // A-splits h,m,l vs B-split h
#pragma unroll
                    for (int T = 0; T < 2; ++T) {
                        c[T] = __builtin_amdgcn_mfma_f32_16x16x32_bf16(ah[T][0], bc0, c[T], 0, 0, 0);
                        c[T] = __builtin_amdgcn_mfma_f32_16x16x32_bf16(ah[T][1], bc1, c[T], 0, 0, 0);
                        c[T] = __builtin_amdgcn_mfma_f32_16x16x32_bf16(am[T][0], bc0, c[T], 0, 0, 0);
                        c[T] = __builtin_amdgcn_mfma_f32_16x16x32_bf16(am[T][1], bc1, c[T], 0, 0, 0);
                        c[T] = __builtin_amdgcn_mfma_f32_16x16x32_bf16(al[T][0], bc0, c[T], 0, 0, 0);
                        c[T] = __builtin_amdgcn_mfma_f32_16x16x32_bf16(al[T][1], bc1, c[T], 0, 0, 0);
                    }
                } else if (es == 1) {  // A-splits h,m vs B-split m
#pragma unroll
                    for (int T = 0; T < 2; ++T) {
                        c[T] = __builtin_amdgcn_mfma_f32_16x16x32_bf16(ah[T][0], bc0, c[T], 0, 0, 0);
                        c[T] = __builtin_amdgcn_mfma_f32_16x16x32_bf16(ah[T][1], bc1, c[T], 0, 0, 0);
                        c[T] = __builtin_amdgcn_mfma_f32_16x16x32_bf16(am[T][0], bc0, c[T], 0, 0, 0);
                        c[T] = __builtin_amdgcn_mfma_f32_16x16x32_bf16(am[T][1], bc1, c[T], 0, 0, 0);
                    }
                } else {  // A-split h vs B-split l
#pragma unroll
                    for (int T = 0; T < 2; ++T) {
                        c[T] = __builtin_amdgcn_mfma_f32_16x16x32_bf16(ah[T][0], bc0, c[T], 0, 0, 0);
                        c[T] = __builtin_amdgcn_mfma_f32_16x16x32_bf16(ah[T][1], bc1, c[T], 0, 0, 0);
                    }
                }
            }
            // top-2 update via min/med3 (7 ops/slot); strict < keeps first-index tie-break
#pragma unroll
            for (int T = 0; T < 2; ++T) {
#pragma unroll
                for (int r = 0; r < 4; ++r) {
                    float s = c[T][r];
                    bool lt1 = s < b1[T][r];
                    bool lt2 = s < b2[T][r];
                    i2[T][r] = lt2 ? (lt1 ? i1[T][r] : code_c) : i2[T][r];
                    b2[T][r] = __builtin_amdgcn_fmed3f(b1[T][r], s, b2[T][r]);
                    i1[T][r] = lt1 ? code_c : i1[T][r];
                    b1[T][r] = fminf(s, b1[T][r]);
                }
            }
        }
    }

    // ---- merge top-2 across the 16 lanes of each row-group (masks 1,2,4,8) ----
#pragma unroll
    for (int T = 0; T < 2; ++T) {
#pragma unroll
        for (int r = 0; r < 4; ++r) {
#pragma unroll
            for (int mask = 1; mask <= 8; mask <<= 1) {
                float q1 = __shfl_xor(b1[T][r], mask);
                int qi1 = __shfl_xor(i1[T][r], mask);
                float q2 = __shfl_xor(b2[T][r], mask);
                int qi2 = __shfl_xor(i2[T][r], mask);
                bool qbest = (q1 < b1[T][r]) || (q1 == b1[T][r] && qi1 < i1[T][r]);
                float c2a = qbest ? b1[T][r] : b2[T][r];
                int c2ai = qbest ? i1[T][r] : i2[T][r];
                float c2b = qbest ? q2 : q1;
                int c2bi = qbest ? qi2 : qi1;
                bool bsec = (c2b < c2a) || (c2b == c2a && c2bi < c2ai);
                b1[T][r] = qbest ? q1 : b1[T][r];
                i1[T][r] = qbest ? qi1 : i1[T][r];
                b2[T][r] = bsec ? c2b : c2a;
                i2[T][r] = bsec ? c2bi : c2ai;
            }
        }
    }
    if (c16 == 0) {  // one writer per 16-lane group: lanes 0,16,32,48
#pragma unroll
        for (int T = 0; T < 2; ++T)
#pragma unroll
            for (int r = 0; r < 4; ++r) {
                unsigned int packed = (unsigned int)i1[T][r] | ((unsigned int)i2[T][r] << 10);
                candout[ptbase + T * 16 + hi * 4 + r] = __uint_as_float(packed);
            }
    }
}

// Rescue: exact fp32 re-score of the two candidates (unchanged, proven absmax=0)
__global__ void vq_rescue_kernel(const float* __restrict__ x, const float* __restrict__ emb,
                                 const float* __restrict__ e2,
                                 float* __restrict__ qout, float* __restrict__ iout) {
    const size_t p = (size_t)blockIdx.x * blockDim.x + threadIdx.x;
    unsigned int cw = __float_as_uint(iout[p]);  // packed candidates from vq_mfma_kernel
    int ca = (int)(cw & 1023u);
    int cb = (int)((cw >> 10) & 1023u);
    const float4* xrow = reinterpret_cast<const float4*>(x + p * DIM);
    const float4* ea = reinterpret_cast<const float4*>(emb + (size_t)ca * DIM);
    const float4* eb = reinterpret_cast<const float4*>(emb + (size_t)cb * DIM);
    float a0 = 0.f, a1 = 0.f, a2 = 0.f, a3 = 0.f;
    float d0 = 0.f, d1 = 0.f, d2 = 0.f, d3 = 0.f;
#pragma unroll
    for (int j = 0; j < DIM / 4; ++j) {
        float4 xv = xrow[j];
        float4 va = ea[j];
        float4 vb = eb[j];
        a0 = fmaf(xv.x, va.x, a0);
        a1 = fmaf(xv.y, va.y, a1);
        a2 = fmaf(xv.z, va.z, a2);
        a3 = fmaf(xv.w, va.w, a3);
        d0 = fmaf(xv.x, vb.x, d0);
        d1 = fmaf(xv.y, vb.y, d1);
        d2 = fmaf(xv.z, vb.z, d2);
        d3 = fmaf(xv.w, vb.w, d3);
    }
    float sa = fmaf(-2.f, (a0 + a1) + (a2 + a3), e2[ca]);
    float sb = fmaf(-2.f, (d0 + d1) + (d2 + d3), e2[cb]);
    bool bwins = (sb < sa) || (sb == sa && cb < ca);
    int win = bwins ? cb : ca;

    const float4* qrow = reinterpret_cast<const float4*>(emb + (size_t)win * DIM);
    float4* orow = reinterpret_cast<float4*>(qout + p * DIM);
#pragma unroll
    for (int j = 0; j < DIM / 4; ++j) orow[j] = qrow[j];
    iout[p] = (float)win;
}

extern "C" void kernel_launch(void* const* d_in, const int* in_sizes, int n_in,
                              void* d_out, int out_size, void* d_ws, size_t ws_size,
                              hipStream_t stream) {
    const float* x = (const float*)d_in[0];    // [N, D] f32
    const float* emb = (const float*)d_in[1];  // [K, D] f32
    float* qout = (float*)d_out;               // [N, D] f32
    float* iout = (float*)d_out + (size_t)NPTS * DIM;  // [N] indices (as float)

    unsigned short* gtile = (unsigned short*)d_ws;
    float* e2g = (float*)((char*)d_ws + E2_OFF);

    vq_e2_kernel<<<(KCODES + 255) / 256, 256, 0, stream>>>(emb, e2g);
    vq_tile_kernel<<<(64 * 3 * 2 * 64 + 255) / 256, 256, 0, stream>>>(emb, gtile);
    vq_mfma_kernel<<<NPTS / 128, 256, 0, stream>>>(x, gtile, e2g, iout);
    vq_rescue_kernel<<<NPTS / 256, 256, 0, stream>>>(x, emb, e2g, qout, iout);
}